// Round 1
// baseline (130.479 us; speedup 1.0000x reference)
//
#include <hip/hip_runtime.h>

// PQC: h = tanh(x @ W^T) * scale; 8-qubit real statevector circuit; <Z_w> outputs.
// One wave = one sample for the circuit: 256 amps = 64 lanes x 4 regs.
// lane bits 5..0 = qubits 0..5 (qubit0 = MSB of state index), reg bits = qubits 6,7.

__device__ __forceinline__ float fast_tanh(float v) {
    float e = __expf(2.0f * v);
    return 1.0f - 2.0f / (e + 1.0f);   // exact at +/-inf overflow
}

__global__ __launch_bounds__(256, 4)
void pqc_kernel(const float* __restrict__ x,
                const float* __restrict__ Wp,
                const float* __restrict__ scalep,
                const float* __restrict__ wts,
                float* __restrict__ out)
{
    __shared__ float hb[64][8];   // per-block projection results

    const int tid  = threadIdx.x;
    const int lane = tid & 63;
    const int wave = tid >> 6;            // 0..3
    const int b0   = blockIdx.x * 64;

    const int s4  = lane >> 4;            // 0..3  sample sub-group
    const int c16 = lane & 15;            // 0..15 column group

    // ---------------- projection phase: this wave's 16 samples ----------------
    const int rbase = b0 + wave * 16;
    float acc[4][8];
    #pragma unroll
    for (int p = 0; p < 4; ++p)
        #pragma unroll
        for (int q = 0; q < 8; ++q) acc[p][q] = 0.0f;

    #pragma unroll 2
    for (int j = 0; j < 12; ++j) {
        const int col4 = j * 16 + c16;    // float4 index within a 768-float row
        float4 wv[8];
        #pragma unroll
        for (int q = 0; q < 8; ++q)
            wv[q] = *reinterpret_cast<const float4*>(Wp + q * 768 + col4 * 4);
        #pragma unroll
        for (int p = 0; p < 4; ++p) {
            const float4 xv = *reinterpret_cast<const float4*>(
                x + (size_t)(rbase + p * 4 + s4) * 768 + col4 * 4);
            #pragma unroll
            for (int q = 0; q < 8; ++q) {
                acc[p][q] = fmaf(xv.x, wv[q].x, acc[p][q]);
                acc[p][q] = fmaf(xv.y, wv[q].y, acc[p][q]);
                acc[p][q] = fmaf(xv.z, wv[q].z, acc[p][q]);
                acc[p][q] = fmaf(xv.w, wv[q].w, acc[p][q]);
            }
        }
    }
    // reduce over the 16 column lanes
    #pragma unroll
    for (int m = 1; m <= 8; m <<= 1)
        #pragma unroll
        for (int p = 0; p < 4; ++p)
            #pragma unroll
            for (int q = 0; q < 8; ++q)
                acc[p][q] += __shfl_xor(acc[p][q], m, 64);

    if (c16 == 0) {
        #pragma unroll
        for (int p = 0; p < 4; ++p) {
            const int srow = wave * 16 + p * 4 + s4;
            #pragma unroll
            for (int q = 0; q < 8; ++q) hb[srow][q] = acc[p][q];
        }
    }
    __syncthreads();

    // ---------------- per-sample angle factors ----------------
    const float scl = scalep[0];
    const int mys = wave * 16 + c16;      // the sample whose angles this lane prepares
    float c8[8], s8[8];
    #pragma unroll
    for (int q = 0; q < 8; ++q) {
        float ang = fast_tanh(hb[mys][q]) * scl + wts[q];   // fold layer-0 weight RY
        __sincosf(0.5f * ang, &s8[q], &c8[q]);
    }
    // fixed layer-1 (second) RY constants — uniform
    float cw[8], sw[8];
    #pragma unroll
    for (int q = 0; q < 8; ++q) {
        float a = 0.5f * wts[8 + q];
        cw[q] = __cosf(a);
        sw[q] = __sinf(a);
    }

    // ---------------- circuit phase: 16 samples, one per pass ----------------
    #pragma unroll 1
    for (int i = 0; i < 16; ++i) {
        float cq[8], sq[8];
        #pragma unroll
        for (int q = 0; q < 8; ++q) {
            cq[q] = __shfl(c8[q], i, 64);
            sq[q] = __shfl(s8[q], i, 64);
        }

        // initial product state (includes folded first RY layers)
        float P = (lane & 32 ? sq[0] : cq[0]);
        P *= (lane & 16 ? sq[1] : cq[1]);
        P *= (lane &  8 ? sq[2] : cq[2]);
        P *= (lane &  4 ? sq[3] : cq[3]);
        P *= (lane &  2 ? sq[4] : cq[4]);
        P *= (lane &  1 ? sq[5] : cq[5]);
        float a0 = P * cq[6] * cq[7];
        float a1 = P * cq[6] * sq[7];
        float a2 = P * sq[6] * cq[7];
        float a3 = P * sq[6] * sq[7];

        // ---- CNOT chain #1: CNOT(q,q+1), q=0..6 ----
        #pragma unroll
        for (int q = 0; q < 5; ++q) {
            const int cm = 1 << (5 - q);
            const int tm = 1 << (4 - q);
            const bool ctl = (lane & cm) != 0;
            float p0 = __shfl_xor(a0, tm, 64);
            float p1 = __shfl_xor(a1, tm, 64);
            float p2 = __shfl_xor(a2, tm, 64);
            float p3 = __shfl_xor(a3, tm, 64);
            a0 = ctl ? p0 : a0;  a1 = ctl ? p1 : a1;
            a2 = ctl ? p2 : a2;  a3 = ctl ? p3 : a3;
        }
        {   // CNOT(5,6): ctrl = lane bit0, target = reg bit1
            const bool ctl = (lane & 1) != 0;
            float t0 = a0, t1 = a1;
            a0 = ctl ? a2 : a0;  a2 = ctl ? t0 : a2;
            a1 = ctl ? a3 : a1;  a3 = ctl ? t1 : a3;
        }
        {   // CNOT(6,7): swap a2<->a3
            float t = a2; a2 = a3; a3 = t;
        }

        // ---- RY layer (second weight layer) ----
        #pragma unroll
        for (int q = 0; q < 6; ++q) {
            const int m = 1 << (5 - q);
            const float ss = (lane & m) ? sw[q] : -sw[q];
            float p0 = __shfl_xor(a0, m, 64);
            float p1 = __shfl_xor(a1, m, 64);
            float p2 = __shfl_xor(a2, m, 64);
            float p3 = __shfl_xor(a3, m, 64);
            a0 = fmaf(cw[q], a0, ss * p0);
            a1 = fmaf(cw[q], a1, ss * p1);
            a2 = fmaf(cw[q], a2, ss * p2);
            a3 = fmaf(cw[q], a3, ss * p3);
        }
        {   // qubit 6: pairs (a0,a2),(a1,a3)
            float n0 = cw[6]*a0 - sw[6]*a2, n2 = fmaf(sw[6], a0, cw[6]*a2);
            float n1 = cw[6]*a1 - sw[6]*a3, n3 = fmaf(sw[6], a1, cw[6]*a3);
            a0 = n0; a2 = n2; a1 = n1; a3 = n3;
        }
        {   // qubit 7: pairs (a0,a1),(a2,a3)
            float n0 = cw[7]*a0 - sw[7]*a1, n1 = fmaf(sw[7], a0, cw[7]*a1);
            float n2 = cw[7]*a2 - sw[7]*a3, n3 = fmaf(sw[7], a2, cw[7]*a3);
            a0 = n0; a1 = n1; a2 = n2; a3 = n3;
        }

        // ---- CNOT chain #2 ----
        #pragma unroll
        for (int q = 0; q < 5; ++q) {
            const int cm = 1 << (5 - q);
            const int tm = 1 << (4 - q);
            const bool ctl = (lane & cm) != 0;
            float p0 = __shfl_xor(a0, tm, 64);
            float p1 = __shfl_xor(a1, tm, 64);
            float p2 = __shfl_xor(a2, tm, 64);
            float p3 = __shfl_xor(a3, tm, 64);
            a0 = ctl ? p0 : a0;  a1 = ctl ? p1 : a1;
            a2 = ctl ? p2 : a2;  a3 = ctl ? p3 : a3;
        }
        {
            const bool ctl = (lane & 1) != 0;
            float t0 = a0, t1 = a1;
            a0 = ctl ? a2 : a0;  a2 = ctl ? t0 : a2;
            a1 = ctl ? a3 : a1;  a3 = ctl ? t1 : a3;
        }
        {
            float t = a2; a2 = a3; a3 = t;
        }

        // ---- measurement: probs and signed sums ----
        float p0 = a0 * a0, p1 = a1 * a1, p2 = a2 * a2, p3 = a3 * a3;
        float t = (p0 + p1) + (p2 + p3);
        float z[8];
        z[0] = (lane & 32) ? -t : t;
        z[1] = (lane & 16) ? -t : t;
        z[2] = (lane &  8) ? -t : t;
        z[3] = (lane &  4) ? -t : t;
        z[4] = (lane &  2) ? -t : t;
        z[5] = (lane &  1) ? -t : t;
        z[6] = (p0 + p1) - (p2 + p3);
        z[7] = (p0 - p1) + (p2 - p3);

        #pragma unroll
        for (int m = 1; m <= 32; m <<= 1)
            #pragma unroll
            for (int q = 0; q < 8; ++q)
                z[q] += __shfl_xor(z[q], m, 64);

        if (lane == 0) {
            float4* o = reinterpret_cast<float4*>(out + (size_t)(rbase + i) * 8);
            o[0] = make_float4(z[0], z[1], z[2], z[3]);
            o[1] = make_float4(z[4], z[5], z[6], z[7]);
        }
    }
}

extern "C" void kernel_launch(void* const* d_in, const int* in_sizes, int n_in,
                              void* d_out, int out_size, void* d_ws, size_t ws_size,
                              hipStream_t stream) {
    const float* x   = (const float*)d_in[0];
    const float* W   = (const float*)d_in[1];
    const float* sc  = (const float*)d_in[2];
    const float* wt  = (const float*)d_in[3];
    float* o         = (float*)d_out;

    const int batch  = in_sizes[0] / 768;     // 65536
    const int blocks = batch / 64;            // 64 samples per block
    pqc_kernel<<<dim3(blocks), dim3(256), 0, stream>>>(x, W, sc, wt, o);
}

// Round 2
// 43.569 us; speedup vs baseline: 2.9948x; 2.9948x over previous
//
#include <hip/hip_runtime.h>

// PQC: h = tanh(x @ W^T) * scale; 8-qubit circuit via exact transfer-matrix
// contraction (CNOT staircase = prefix-XOR => MPS bond dim 2 per staircase;
// <Z_i> = 1D chain contraction with 2x2x2 state, symmetry-reduced to 2x3).
// Per-sample cost ~700 thread-local FMAs, no cross-lane ops at all.

__device__ __forceinline__ float fast_tanh(float v) {
    float e = __expf(2.0f * v);
    return 1.0f - 2.0f / (e + 1.0f);   // exact at +/-inf overflow
}

__global__ __launch_bounds__(256, 3)
void pqc_kernel(const float* __restrict__ x,
                const float* __restrict__ Wp,
                const float* __restrict__ scalep,
                const float* __restrict__ wts,
                float* __restrict__ out)
{
    __shared__ float hb[64][8];   // per-block projection results (pre-tanh)

    const int tid  = threadIdx.x;
    const int lane = tid & 63;
    const int wave = tid >> 6;            // 0..3
    const int b0   = blockIdx.x * 64;

    const int s4  = lane >> 4;            // 0..3  sample sub-group
    const int c16 = lane & 15;            // 0..15 column group

    // ---------------- projection phase: this wave's 16 samples ----------------
    const int rbase = b0 + wave * 16;
    float acc[4][8];
    #pragma unroll
    for (int p = 0; p < 4; ++p)
        #pragma unroll
        for (int q = 0; q < 8; ++q) acc[p][q] = 0.0f;

    #pragma unroll 2
    for (int j = 0; j < 12; ++j) {
        const int col4 = j * 16 + c16;    // float4 index within a 768-float row
        float4 wv[8];
        #pragma unroll
        for (int q = 0; q < 8; ++q)
            wv[q] = *reinterpret_cast<const float4*>(Wp + q * 768 + col4 * 4);
        #pragma unroll
        for (int p = 0; p < 4; ++p) {
            const float4 xv = *reinterpret_cast<const float4*>(
                x + (size_t)(rbase + p * 4 + s4) * 768 + col4 * 4);
            #pragma unroll
            for (int q = 0; q < 8; ++q) {
                acc[p][q] = fmaf(xv.x, wv[q].x, acc[p][q]);
                acc[p][q] = fmaf(xv.y, wv[q].y, acc[p][q]);
                acc[p][q] = fmaf(xv.z, wv[q].z, acc[p][q]);
                acc[p][q] = fmaf(xv.w, wv[q].w, acc[p][q]);
            }
        }
    }
    // reduce over the 16 column lanes
    #pragma unroll
    for (int m = 1; m <= 8; m <<= 1)
        #pragma unroll
        for (int p = 0; p < 4; ++p)
            #pragma unroll
            for (int q = 0; q < 8; ++q)
                acc[p][q] += __shfl_xor(acc[p][q], m, 64);

    if (c16 == 0) {
        #pragma unroll
        for (int p = 0; p < 4; ++p) {
            const int srow = wave * 16 + p * 4 + s4;
            #pragma unroll
            for (int q = 0; q < 8; ++q) hb[srow][q] = acc[p][q];
        }
    }
    __syncthreads();

    // ---------------- circuit phase: transfer-matrix, one sample per thread ----
    // Active: lanes 0..15 of each wave -> 64 samples per block, one per thread.
    if (lane < 16) {
        const int sl   = wave * 16 + lane;     // local sample 0..63
        const int samp = b0 + sl;
        const float scl = scalep[0];

        // per-sample single-qubit input amplitudes: f0=cos(phi/2), f1=sin(phi/2)
        // phi folds the data RY and the layer-0 weight RY (both pre-entangler).
        float f0[8], f1[8];
        #pragma unroll
        for (int q = 0; q < 8; ++q) {
            float ang = fast_tanh(hb[sl][q]) * scl + wts[q];
            __sincosf(0.5f * ang, &f1[q], &f0[q]);
        }
        // layer-1 RY params (uniform): G-tables c^2, s^2, c*s
        float c2[8], s2[8], cs[8];
        #pragma unroll
        for (int q = 0; q < 8; ++q) {
            float sw, cw;
            __sincosf(0.5f * wts[8 + q], &sw, &cw);
            c2[q] = cw * cw; s2[q] = sw * sw; cs[q] = cw * sw;
        }

        // state vector over (b, sym(beta,beta~)): [2][3], t: 0=(00),1=(01/10),2=(11)
        // prefix sweep: Lp[q] = L^(q); Lp[0] = e_{b=0,t=0}
        float Lp[9][2][3];
        Lp[0][0][0] = 1.f; Lp[0][0][1] = 0.f; Lp[0][0][2] = 0.f;
        Lp[0][1][0] = 0.f; Lp[0][1][1] = 0.f; Lp[0][1][2] = 0.f;

        #pragma unroll
        for (int q = 0; q < 8; ++q) {
            const float A = f0[q] * f0[q];
            const float B = f0[q] * f1[q];
            const float C = f1[q] * f1[q];
            float u[2][3];
            #pragma unroll
            for (int b = 0; b < 2; ++b) {
                const float v0 = Lp[q][b][0], v1 = Lp[q][b][1], v2 = Lp[q][b][2];
                u[b][0] = A * v0 + 2.f * B * v1 + C * v2;
                u[b][1] = B * v0 + (A + C) * v1 + B * v2;
                u[b][2] = C * v0 + 2.f * B * v1 + A * v2;
            }
            Lp[q+1][0][0] = c2[q] * u[0][0] + s2[q] * u[1][0];
            Lp[q+1][1][0] = s2[q] * u[0][0] + c2[q] * u[1][0];
            const float m = cs[q] * (u[1][1] - u[0][1]);
            Lp[q+1][0][1] = m;
            Lp[q+1][1][1] = -m;
            Lp[q+1][0][2] = s2[q] * u[0][2] + c2[q] * u[1][2];
            Lp[q+1][1][2] = c2[q] * u[0][2] + s2[q] * u[1][2];
        }

        // suffix sweep + signed dots: z_i = <S^(i+1), (+/- on b) L^(i+1)>
        float S[2][3] = {{1.f, 1.f, 1.f}, {1.f, 1.f, 1.f}};
        float z[8];
        #pragma unroll
        for (int i = 7; i >= 0; --i) {
            z[i] = (S[0][0] * Lp[i+1][0][0] + 2.f * S[0][1] * Lp[i+1][0][1] + S[0][2] * Lp[i+1][0][2])
                 - (S[1][0] * Lp[i+1][1][0] + 2.f * S[1][1] * Lp[i+1][1][1] + S[1][2] * Lp[i+1][1][2]);
            if (i > 0) {
                float u[2][3];
                u[0][0] = c2[i] * S[0][0] + s2[i] * S[1][0];
                u[1][0] = s2[i] * S[0][0] + c2[i] * S[1][0];
                const float m = cs[i] * (S[1][1] - S[0][1]);
                u[0][1] = m; u[1][1] = -m;
                u[0][2] = s2[i] * S[0][2] + c2[i] * S[1][2];
                u[1][2] = c2[i] * S[0][2] + s2[i] * S[1][2];
                const float A = f0[i] * f0[i];
                const float B = f0[i] * f1[i];
                const float C = f1[i] * f1[i];
                #pragma unroll
                for (int b = 0; b < 2; ++b) {
                    const float u0 = u[b][0], u1 = u[b][1], u2 = u[b][2];
                    S[b][0] = A * u0 + 2.f * B * u1 + C * u2;
                    S[b][1] = B * u0 + (A + C) * u1 + B * u2;
                    S[b][2] = C * u0 + 2.f * B * u1 + A * u2;
                }
            }
        }

        float4* o = reinterpret_cast<float4*>(out + (size_t)samp * 8);
        o[0] = make_float4(z[0], z[1], z[2], z[3]);
        o[1] = make_float4(z[4], z[5], z[6], z[7]);
    }
}

extern "C" void kernel_launch(void* const* d_in, const int* in_sizes, int n_in,
                              void* d_out, int out_size, void* d_ws, size_t ws_size,
                              hipStream_t stream) {
    const float* x   = (const float*)d_in[0];
    const float* W   = (const float*)d_in[1];
    const float* sc  = (const float*)d_in[2];
    const float* wt  = (const float*)d_in[3];
    float* o         = (float*)d_out;

    const int batch  = in_sizes[0] / 768;     // 65536
    const int blocks = batch / 64;            // 64 samples per block
    pqc_kernel<<<dim3(blocks), dim3(256), 0, stream>>>(x, W, sc, wt, o);
}